// Round 4
// baseline (89.479 us; speedup 1.0000x reference)
//
#include <hip/hip_runtime.h>
#include <hip/hip_bf16.h>
#include <cstddef>

#define B_ 32
#define T_ 128
#define N_ 200
#define FI_ 32
#define FO_ 64
#define K_ 3
#define NB_ 2     // batches per block (share staged W, pipeline A)

typedef __attribute__((ext_vector_type(8))) short short8;            // 8 bf16
typedef __attribute__((ext_vector_type(8))) unsigned short ushort8;
typedef __attribute__((ext_vector_type(4))) float f32x4;

// LDS layout (ushort units). Row stride 40 ushorts = 80 B -> worst 2-way bank
// aliasing (free, m136). A double-buffered for the NB=2 pipeline.
#define AROW_ 40
#define A_ROWS_ (T_ + 2)          // t = -1 .. 128, zero-padded edges
#define ABUF_ (A_ROWS_ * AROW_)   // 5200 ushorts per buffer
#define B_OFF_ (2 * ABUF_)        // 10400
#define BROW_ 40
#define BK_SZ_ (FO_ * BROW_)      // 2560 ushorts per tap k
#define NSLOT_ (A_ROWS_ * 4)      // 520 ushort8 staging slots per A tile

__device__ __forceinline__ unsigned short f2bf(float f) {
    union { __hip_bfloat16 h; unsigned short u; } cv;
    cv.h = __float2bfloat16(f);
    return cv.u;
}

__device__ __forceinline__ f32x4 mfma16(short8 a, short8 b, f32x4 c) {
    return __builtin_amdgcn_mfma_f32_16x16x32_bf16(a, b, c, 0, 0, 0);
}

__device__ __forceinline__ void compute_tile(
    const unsigned short* __restrict__ lds, int abase,
    int wv, int lane, f32x4 acc[2][4])
{
    const int row16 = lane & 15;
    const int grp = lane >> 4;
    #pragma unroll
    for (int k = 0; k < K_; ++k) {
        const short8 a0 = *reinterpret_cast<const short8*>(
            &lds[abase + (wv * 32 + 0  + row16 + k) * AROW_ + grp * 8]);
        const short8 a1 = *reinterpret_cast<const short8*>(
            &lds[abase + (wv * 32 + 16 + row16 + k) * AROW_ + grp * 8]);
        #pragma unroll
        for (int j = 0; j < 4; ++j) {
            const short8 bf = *reinterpret_cast<const short8*>(
                &lds[B_OFF_ + k * BK_SZ_ + (j * 16 + row16) * BROW_ + grp * 8]);
            acc[0][j] = mfma16(a0, bf, acc[0][j]);
            acc[1][j] = mfma16(a1, bf, acc[1][j]);
        }
    }
}

__device__ __forceinline__ void store_tile(
    float* __restrict__ out, int b, int n, int wv, int lane,
    const float bvj[4], f32x4 acc[2][4])
{
    const int row16 = lane & 15;
    const int grp = lane >> 4;
    #pragma unroll
    for (int j = 0; j < 4; ++j) {
        #pragma unroll
        for (int m = 0; m < 2; ++m) {
            #pragma unroll
            for (int r = 0; r < 4; ++r) {
                const int t = wv * 32 + m * 16 + grp * 4 + r;
                out[(((size_t)b * T_ + t) * N_ + n) * FO_ + j * 16 + row16] =
                    acc[m][j][r] + bvj[j];
            }
        }
    }
}

// One block per (n, pair-of-b). Grid is n-fastest so concurrently-resident
// blocks cover all 200 n for a few b -> contiguous DRAM coverage for both
// the strided 128B x-reads and 256B out-writes (page-locality theory, R4).
__global__ __launch_bounds__(256, 4) void multiconv_mfma(
    const float* __restrict__ x, const float* __restrict__ w,
    const float* __restrict__ bias, float* __restrict__ out)
{
    __shared__ __align__(16) unsigned short lds[B_OFF_ + K_ * BK_SZ_]; // 36160 B

    const int bid = blockIdx.x;
    const int n = bid % N_;
    const int bp = bid / N_;
    const int b0 = bp * NB_;
    const int b1 = b0 + 1;
    const int tid = threadIdx.x;
    const int lane = tid & 63;
    const int wv = tid >> 6;

    // ---- stage w[n,f,i,k] -> B_lds[k][f][i] bf16 (i contiguous per lane) ----
    {
        const int f = tid >> 2;
        const int i0 = (tid & 3) * 8;
        const float* wp = w + ((size_t)n * FO_ + f) * (FI_ * K_) + (size_t)i0 * K_;
        float v[24];
        #pragma unroll
        for (int j = 0; j < 6; ++j) {
            const float4 t4 = *reinterpret_cast<const float4*>(&wp[j * 4]);
            v[j*4+0] = t4.x; v[j*4+1] = t4.y; v[j*4+2] = t4.z; v[j*4+3] = t4.w;
        }
        #pragma unroll
        for (int k = 0; k < K_; ++k) {
            ushort8 u;
            #pragma unroll
            for (int j = 0; j < 8; ++j) u[j] = f2bf(v[j * K_ + k]);
            *reinterpret_cast<ushort8*>(&lds[B_OFF_ + k * BK_SZ_ + f * BROW_ + i0]) = u;
        }
    }

    // ---- stage x[b0] rows t=-1..128 as bf16 into A buf0 ----
    const float* xb0 = x + ((size_t)b0 * T_ * N_ + n) * FI_;
    const float* xb1 = x + ((size_t)b1 * T_ * N_ + n) * FI_;
    #pragma unroll
    for (int ss = 0; ss < 3; ++ss) {
        const int s = tid + ss * 256;
        if (ss < 2 || tid < NSLOT_ - 512) {
            const int rr = s >> 2, q = s & 3;
            const int t = rr - 1;
            ushort8 u = (ushort8)0;
            if (t >= 0 && t < T_) {
                const float4 v0 = *reinterpret_cast<const float4*>(
                    &xb0[(size_t)t * N_ * FI_ + q * 8]);
                const float4 v1 = *reinterpret_cast<const float4*>(
                    &xb0[(size_t)t * N_ * FI_ + q * 8 + 4]);
                u[0] = f2bf(v0.x); u[1] = f2bf(v0.y); u[2] = f2bf(v0.z); u[3] = f2bf(v0.w);
                u[4] = f2bf(v1.x); u[5] = f2bf(v1.y); u[6] = f2bf(v1.z); u[7] = f2bf(v1.w);
            }
            *reinterpret_cast<ushort8*>(&lds[rr * AROW_ + q * 8]) = u;
        }
    }

    __syncthreads();

    // ---- T14-lite: issue b1's x loads into regs NOW; LDS-write after b0 MFMA ----
    float4 nv[6];
    #pragma unroll
    for (int ss = 0; ss < 3; ++ss) {
        const int s = tid + ss * 256;
        if (ss < 2 || tid < NSLOT_ - 512) {
            const int rr = s >> 2, q = s & 3;
            const int t = rr - 1;
            if (t >= 0 && t < T_) {
                nv[ss*2]   = *reinterpret_cast<const float4*>(
                    &xb1[(size_t)t * N_ * FI_ + q * 8]);
                nv[ss*2+1] = *reinterpret_cast<const float4*>(
                    &xb1[(size_t)t * N_ * FI_ + q * 8 + 4]);
            }
        }
    }

    const int row16 = lane & 15;
    float bvj[4];
    #pragma unroll
    for (int j = 0; j < 4; ++j) bvj[j] = bias[n * FO_ + j * 16 + row16];

    // ---- compute b0 ----
    f32x4 acc[2][4];
    #pragma unroll
    for (int m = 0; m < 2; ++m)
        #pragma unroll
        for (int j = 0; j < 4; ++j) acc[m][j] = (f32x4){0.f, 0.f, 0.f, 0.f};
    compute_tile(lds, 0, wv, lane, acc);

    // ---- convert + LDS-write b1's A into buf1 (waits vmcnt internally) ----
    #pragma unroll
    for (int ss = 0; ss < 3; ++ss) {
        const int s = tid + ss * 256;
        if (ss < 2 || tid < NSLOT_ - 512) {
            const int rr = s >> 2, q = s & 3;
            const int t = rr - 1;
            ushort8 u = (ushort8)0;
            if (t >= 0 && t < T_) {
                const float4 v0 = nv[ss*2], v1 = nv[ss*2+1];
                u[0] = f2bf(v0.x); u[1] = f2bf(v0.y); u[2] = f2bf(v0.z); u[3] = f2bf(v0.w);
                u[4] = f2bf(v1.x); u[5] = f2bf(v1.y); u[6] = f2bf(v1.z); u[7] = f2bf(v1.w);
            }
            *reinterpret_cast<ushort8*>(&lds[ABUF_ + rr * AROW_ + q * 8]) = u;
        }
    }

    // ---- store b0 while b1's LDS writes drain ----
    store_tile(out, b0, n, wv, lane, bvj, acc);

    __syncthreads();

    // ---- compute + store b1 ----
    #pragma unroll
    for (int m = 0; m < 2; ++m)
        #pragma unroll
        for (int j = 0; j < 4; ++j) acc[m][j] = (f32x4){0.f, 0.f, 0.f, 0.f};
    compute_tile(lds, ABUF_, wv, lane, acc);
    store_tile(out, b1, n, wv, lane, bvj, acc);
}

extern "C" void kernel_launch(void* const* d_in, const int* in_sizes, int n_in,
                              void* d_out, int out_size, void* d_ws, size_t ws_size,
                              hipStream_t stream) {
    const float* x    = (const float*)d_in[0];
    const float* w    = (const float*)d_in[1];
    const float* bias = (const float*)d_in[2];
    float* out = (float*)d_out;

    const int grid = (B_ / NB_) * N_;  // 3200 blocks: (bp, n), n fastest
    multiconv_mfma<<<grid, 256, 0, stream>>>(x, w, bias, out);
}